// Round 1
// baseline (332.000 us; speedup 1.0000x reference)
//
#include <hip/hip_runtime.h>
#include <hip/hip_bf16.h>

#define NROWS 16384
#define NCODES 8192
#define DIM 256
#define BM 64                      // rows per block
#define SPLITS 4
#define CPB (NCODES / SPLITS)      // 2048 codes per block
#define CAP 24
#define MARGIN 3.0e-4f

#define WFRAG_BLOCKS 1024          // 8192*256/8 / 256
#define SQ_BLOCKS 1536             // (16384+8192) rows / 16 per block

typedef __attribute__((ext_vector_type(8))) short bf16x8;
typedef __attribute__((ext_vector_type(4))) float f32x4;

__device__ inline unsigned short f2bf(float f) {
    union { __hip_bfloat16 h; unsigned short u; } cv;
    cv.h = __float2bfloat16(f);
    return cv.u;
}
__device__ inline unsigned f2ord(float f) {
    unsigned u = __float_as_uint(f);
    return u ^ ((u >> 31) ? 0xFFFFFFFFu : 0x80000000u);
}
__device__ inline float ord2f(unsigned u) {
    unsigned v = (u & 0x80000000u) ? (u ^ 0x80000000u) : ~u;
    return __uint_as_float(v);
}

// Fused prep:
//  blocks [0, WFRAG_BLOCKS): pre-swizzle W into MFMA B-fragment order (bf16).
//    flat unit tid = (k32*512 + c16)*64 + L holds 8 bf16 =
//      W[c16*16 + (L&15)][k32*32 + (L>>4)*8 + j]
//  blocks [WFRAG_BLOCKS, +SQ_BLOCKS): xsq/wsq via the EXACT pairwise256 tree
//    (validated round 2), parallelized 16 lanes/row: lane c owns chain
//    r[j], h (j=c&7, h=c>>3) = sum_g x[h*128+g*8+j]^2 in sequential g order;
//    the shfl-xor tree reproduces ((r0+r1)+(r2+r3))+((r4+r5)+(r6+r7)) and
//    res0+res1 bit-exactly (fp add is operand-commutative).
//    Also initializes best64g (replaces hipMemsetAsync).
__global__ __launch_bounds__(256)
void prep_kernel(const float* __restrict__ x, const float* __restrict__ w,
                 unsigned short* __restrict__ whf,
                 float* __restrict__ xsq, float* __restrict__ wsq,
                 unsigned long long* __restrict__ best64g) {
    if (blockIdx.x < WFRAG_BLOCKS) {
        int tid = blockIdx.x * 256 + threadIdx.x;   // 0 .. 262143
        int L = tid & 63;
        int rest = tid >> 6;
        int c16 = rest & 511;
        int k32 = rest >> 9;
        int code = c16 * 16 + (L & 15);
        int k = k32 * 32 + (L >> 4) * 8;
        const float4* p = reinterpret_cast<const float4*>(w + (size_t)code * DIM + k);
        float4 u0 = p[0], u1 = p[1];
        unsigned short tmp[8];
        tmp[0] = f2bf(u0.x); tmp[1] = f2bf(u0.y); tmp[2] = f2bf(u0.z); tmp[3] = f2bf(u0.w);
        tmp[4] = f2bf(u1.x); tmp[5] = f2bf(u1.y); tmp[6] = f2bf(u1.z); tmp[7] = f2bf(u1.w);
        *reinterpret_cast<uint4*>(whf + (size_t)tid * 8) = *reinterpret_cast<uint4*>(tmp);
    } else {
        int blk = blockIdx.x - WFRAG_BLOCKS;
        int row = blk * 16 + (threadIdx.x >> 4);     // 0 .. 24575
        int c = threadIdx.x & 15;
        int j = c & 7, h = c >> 3;
        const float* src = (row < NROWS) ? (x + (size_t)row * DIM)
                                         : (w + (size_t)(row - NROWS) * DIM);
        const float* base = src + h * 128 + j;
        float r = 0.0f;
        #pragma unroll
        for (int g = 0; g < 16; ++g) {
            float v = base[g * 8];
            r = __fadd_rn(r, __fmul_rn(v, v));
        }
        float t;
        t = __shfl_xor(r, 1, 64); r = __fadd_rn(r, t);   // (r_j + r_{j^1})
        t = __shfl_xor(r, 2, 64); r = __fadd_rn(r, t);   // (r0+r1)+(r2+r3)
        t = __shfl_xor(r, 4, 64); r = __fadd_rn(r, t);   // half sum
        t = __shfl_xor(r, 8, 64); r = __fadd_rn(r, t);   // res0 + res1
        if (c == 0) {
            if (row < NROWS) xsq[row] = r;
            else wsq[row - NROWS] = r;
        }
        if (c == 1 && row < NROWS) best64g[row] = 0xFFFFFFFFFFFFFFFFULL;
    }
}

// Main: 256 thr (4 waves), BM=64 rows, CPB=2048 codes, acc 4rg x 4cf (64 AGPR)
// -> ~155 unified regs -> 3 blocks/CU (12 waves/CU) vs previous 8 waves/CU.
// A-tile in LDS, B global->reg double-buffered, barrier-free K-loop.
__global__ __launch_bounds__(256, 3)
void vq_main(const float* __restrict__ x, const float* __restrict__ w,
             const unsigned short* __restrict__ whf,
             const float* __restrict__ wsq, const float* __restrict__ xsq,
             unsigned long long* __restrict__ best64g) {
    __shared__ unsigned short afrag[4 * 8 * 64 * 8];   // rg,k32,lane -> 16B frag; 32 KB
    __shared__ unsigned rowmin[BM];
    __shared__ int cnt[BM];
    __shared__ int cand[BM][CAP];

    const int tid = threadIdx.x;
    const int lane = tid & 63;
    const int wv = tid >> 6;          // 0..3
    const int lm = lane & 15;
    const int lq = lane >> 4;

    // block -> (split, rowGroup); same-split blocks cluster per XCD pair
    // (each XCD reads 1 MB of whf -> L2-resident)
    const int blk = blockIdx.x;               // 0..1023
    const int xcd = blk & 7;
    const int split = xcd & 3;
    const int rowGroup = (xcd >> 2) * 128 + (blk >> 3);   // bijective 0..255 per split
    const int rowBase = rowGroup * BM;
    const int codeBase = split * CPB;

    if (tid < BM) { rowmin[tid] = 0xFFFFFFFFu; cnt[tid] = 0; }

    // ---- stage A tile once (bf16, fragment order); wave wv handles rg=wv ----
    {
        const int rg = wv;
        const float* xr = x + (size_t)(rowBase + rg * 16 + lm) * DIM + lq * 8;
        #pragma unroll
        for (int k32 = 0; k32 < 8; ++k32) {
            float4 u0 = *reinterpret_cast<const float4*>(xr + k32 * 32);
            float4 u1 = *reinterpret_cast<const float4*>(xr + k32 * 32 + 4);
            unsigned short t8[8];
            t8[0] = f2bf(u0.x); t8[1] = f2bf(u0.y); t8[2] = f2bf(u0.z); t8[3] = f2bf(u0.w);
            t8[4] = f2bf(u1.x); t8[5] = f2bf(u1.y); t8[6] = f2bf(u1.z); t8[7] = f2bf(u1.w);
            *reinterpret_cast<uint4*>(afrag + ((rg * 8 + k32) * 64 + lane) * 8) =
                *reinterpret_cast<uint4*>(t8);
        }
    }
    __syncthreads();   // the ONLY barrier before the final reduction

    const int waveCode16 = (codeBase >> 4) + wv * 32;    // base c16 for this wave

    for (int p = 0; p < 8; ++p) {                        // 8 passes x 64 codes
        const int pbase16 = waveCode16 + p * 4;
        f32x4 acc[4][4];
        #pragma unroll
        for (int rg = 0; rg < 4; ++rg)
            #pragma unroll
            for (int cf = 0; cf < 4; ++cf)
                acc[rg][cf] = (f32x4){0.f, 0.f, 0.f, 0.f};

        // hoist wsq loads for the epilogue (hide L2 latency under the K-loop)
        float wq[4];
        #pragma unroll
        for (int cf = 0; cf < 4; ++cf)
            wq[cf] = wsq[(pbase16 + cf) * 16 + lm];

        bf16x8 bb[2][4];
        #pragma unroll
        for (int cf = 0; cf < 4; ++cf)
            bb[0][cf] = *reinterpret_cast<const bf16x8*>(
                whf + (((size_t)(pbase16 + cf)) * 64 + lane) * 8);

        #pragma unroll
        for (int k32 = 0; k32 < 8; ++k32) {
            const int cur = k32 & 1;
            if (k32 < 7) {
                #pragma unroll
                for (int cf = 0; cf < 4; ++cf)
                    bb[cur ^ 1][cf] = *reinterpret_cast<const bf16x8*>(
                        whf + (((size_t)((k32 + 1) * 512 + pbase16 + cf)) * 64 + lane) * 8);
            }
            bf16x8 a[4];
            #pragma unroll
            for (int rg = 0; rg < 4; ++rg)
                a[rg] = *reinterpret_cast<const bf16x8*>(
                    afrag + ((rg * 8 + k32) * 64 + lane) * 8);
            #pragma unroll
            for (int cf = 0; cf < 4; ++cf)
                #pragma unroll
                for (int rg = 0; rg < 4; ++rg)
                    acc[rg][cf] = __builtin_amdgcn_mfma_f32_16x16x32_bf16(
                        a[rg], bb[cur][cf], acc[rg][cf], 0, 0, 0);
        }

        // ---- approx score: s = wsq - 2*dot ----
        float mloc[16];
        #pragma unroll
        for (int rg = 0; rg < 4; ++rg) {
            #pragma unroll
            for (int r = 0; r < 4; ++r) {
                float m = __builtin_huge_valf();
                #pragma unroll
                for (int cf = 0; cf < 4; ++cf)
                    m = fminf(m, fmaf(-2.f, acc[rg][cf][r], wq[cf]));
                mloc[rg * 4 + r] = m;
                float rm = m;
                rm = fminf(rm, __shfl_xor(rm, 1, 64));
                rm = fminf(rm, __shfl_xor(rm, 2, 64));
                rm = fminf(rm, __shfl_xor(rm, 4, 64));
                rm = fminf(rm, __shfl_xor(rm, 8, 64));
                if (lm == 0)
                    atomicMin(&rowmin[rg * 16 + lq * 4 + r], f2ord(rm));
            }
        }
        // collect candidates vs prefix min (stale rowmin => superset, safe)
        #pragma unroll
        for (int rg = 0; rg < 4; ++rg) {
            #pragma unroll
            for (int r = 0; r < 4; ++r) {
                const int row = rg * 16 + lq * 4 + r;
                float limit = ord2f(rowmin[row]) + MARGIN;
                if (mloc[rg * 4 + r] <= limit) {
                    #pragma unroll
                    for (int cf = 0; cf < 4; ++cf) {
                        float s = fmaf(-2.f, acc[rg][cf][r], wq[cf]);
                        if (s <= limit) {
                            int pos = atomicAdd(&cnt[row], 1);
                            if (pos < CAP)
                                cand[row][pos] = (pbase16 + cf) * 16 + lm;
                        }
                    }
                }
            }
        }
    }
    __syncthreads();

    // ---- exact rescore (bit-identical to round-2 validated formula) ----
    for (int slot = tid; slot < BM * CAP; slot += 256) {
        int row = slot / CAP, pos = slot - (slot / CAP) * CAP;
        int n = cnt[row] < CAP ? cnt[row] : CAP;
        if (pos < n) {
            int c = cand[row][pos];
            const float* xr = x + (size_t)(rowBase + row) * DIM;
            const float* wr = w + (size_t)c * DIM;
            float d = 0.f;
            for (int k = 0; k < DIM; k += 4) {
                float4 a = *reinterpret_cast<const float4*>(xr + k);
                float4 b = *reinterpret_cast<const float4*>(wr + k);
                d = fmaf(a.x, b.x, d);
                d = fmaf(a.y, b.y, d);
                d = fmaf(a.z, b.z, d);
                d = fmaf(a.w, b.w, d);
            }
            float t1 = __fadd_rn(xsq[rowBase + row], wsq[c]);
            float s = __fsub_rn(t1, __fadd_rn(d, d));
            unsigned long long key =
                ((unsigned long long)__float_as_uint(s) << 32) | (unsigned)c;
            atomicMin(best64g + rowBase + row, key);   // s>0: bit order = float order
        }
    }
}

// Final: read per-row best key, write index + gather codeword.
__global__ __launch_bounds__(256)
void out_kernel(const float* __restrict__ w,
                const unsigned long long* __restrict__ best64g,
                float* __restrict__ out_q, float* __restrict__ out_idx) {
    int r = blockIdx.x * 4 + (threadIdx.x >> 6);
    int lane = threadIdx.x & 63;
    unsigned long long key = best64g[r];
    int idx = (int)(key & 0xFFFFFFFFu);
    float4 v = reinterpret_cast<const float4*>(w + (size_t)idx * DIM)[lane];
    reinterpret_cast<float4*>(out_q + (size_t)r * DIM)[lane] = v;
    if (lane == 0) out_idx[r] = (float)idx;
}

extern "C" void kernel_launch(void* const* d_in, const int* in_sizes, int n_in,
                              void* d_out, int out_size, void* d_ws, size_t ws_size,
                              hipStream_t stream) {
    const float* x = (const float*)d_in[0];   // (16384, 256) fp32
    const float* w = (const float*)d_in[1];   // (8192, 256) fp32
    float* out_q = (float*)d_out;
    float* out_idx = (float*)d_out + (size_t)NROWS * DIM;

    unsigned short* whf = (unsigned short*)d_ws;                      // 4 MB
    float* wsq = (float*)((char*)d_ws + (size_t)NCODES * DIM * 2);    // 32 KB
    float* xsq = wsq + NCODES;                                        // 64 KB
    unsigned long long* best64g = (unsigned long long*)(xsq + NROWS); // 128 KB

    prep_kernel<<<WFRAG_BLOCKS + SQ_BLOCKS, 256, 0, stream>>>(x, w, whf, xsq, wsq, best64g);
    vq_main<<<(NROWS / BM) * SPLITS, 256, 0, stream>>>(x, w, whf, wsq, xsq, best64g);
    out_kernel<<<NROWS / 4, 256, 0, stream>>>(w, best64g, out_q, out_idx);
}

// Round 2
// 229.814 us; speedup vs baseline: 1.4446x; 1.4446x over previous
//
#include <hip/hip_runtime.h>
#include <hip/hip_bf16.h>

#define NROWS 16384
#define NCODES 8192
#define DIM 256
#define BM 128                     // rows per block
#define SPLITS 2
#define CPB (NCODES / SPLITS)      // 4096 codes per block
#define CAP 24
#define MARGIN 3.0e-4f

#define WFRAG_BLOCKS 1024          // 8192*256/8 / 256
#define SQ_BLOCKS 1536             // (16384+8192) rows / 16 per block

typedef __attribute__((ext_vector_type(8))) short bf16x8;
typedef __attribute__((ext_vector_type(4))) float f32x4;

__device__ inline unsigned short f2bf(float f) {
    union { __hip_bfloat16 h; unsigned short u; } cv;
    cv.h = __float2bfloat16(f);
    return cv.u;
}
__device__ inline unsigned f2ord(float f) {
    unsigned u = __float_as_uint(f);
    return u ^ ((u >> 31) ? 0xFFFFFFFFu : 0x80000000u);
}
__device__ inline float ord2f(unsigned u) {
    unsigned v = (u & 0x80000000u) ? (u ^ 0x80000000u) : ~u;
    return __uint_as_float(v);
}

// Fused prep (validated round 1, absmax 0.0):
//  blocks [0, WFRAG_BLOCKS): pre-swizzle W into MFMA fragment order (bf16).
//    flat unit tid = (k32*512 + c16)*64 + L holds 8 bf16 =
//      W[c16*16 + (L&15)][k32*32 + (L>>4)*8 + j]
//  blocks [WFRAG_BLOCKS, +SQ_BLOCKS): xsq/wsq via the EXACT pairwise256 tree,
//    16 lanes/row, shfl-xor combine (bit-exact; fp add operand-commutative).
//    Also initializes best64g (replaces hipMemsetAsync).
__global__ __launch_bounds__(256)
void prep_kernel(const float* __restrict__ x, const float* __restrict__ w,
                 unsigned short* __restrict__ whf,
                 float* __restrict__ xsq, float* __restrict__ wsq,
                 unsigned long long* __restrict__ best64g) {
    if (blockIdx.x < WFRAG_BLOCKS) {
        int tid = blockIdx.x * 256 + threadIdx.x;   // 0 .. 262143
        int L = tid & 63;
        int rest = tid >> 6;
        int c16 = rest & 511;
        int k32 = rest >> 9;
        int code = c16 * 16 + (L & 15);
        int k = k32 * 32 + (L >> 4) * 8;
        const float4* p = reinterpret_cast<const float4*>(w + (size_t)code * DIM + k);
        float4 u0 = p[0], u1 = p[1];
        unsigned short tmp[8];
        tmp[0] = f2bf(u0.x); tmp[1] = f2bf(u0.y); tmp[2] = f2bf(u0.z); tmp[3] = f2bf(u0.w);
        tmp[4] = f2bf(u1.x); tmp[5] = f2bf(u1.y); tmp[6] = f2bf(u1.z); tmp[7] = f2bf(u1.w);
        *reinterpret_cast<uint4*>(whf + (size_t)tid * 8) = *reinterpret_cast<uint4*>(tmp);
    } else {
        int blk = blockIdx.x - WFRAG_BLOCKS;
        int row = blk * 16 + (threadIdx.x >> 4);     // 0 .. 24575
        int c = threadIdx.x & 15;
        int j = c & 7, h = c >> 3;
        const float* src = (row < NROWS) ? (x + (size_t)row * DIM)
                                         : (w + (size_t)(row - NROWS) * DIM);
        const float* base = src + h * 128 + j;
        float r = 0.0f;
        #pragma unroll
        for (int g = 0; g < 16; ++g) {
            float v = base[g * 8];
            r = __fadd_rn(r, __fmul_rn(v, v));
        }
        float t;
        t = __shfl_xor(r, 1, 64); r = __fadd_rn(r, t);   // (r_j + r_{j^1})
        t = __shfl_xor(r, 2, 64); r = __fadd_rn(r, t);   // (r0+r1)+(r2+r3)
        t = __shfl_xor(r, 4, 64); r = __fadd_rn(r, t);   // half sum
        t = __shfl_xor(r, 8, 64); r = __fadd_rn(r, t);   // res0 + res1
        if (c == 0) {
            if (row < NROWS) xsq[row] = r;
            else wsq[row - NROWS] = r;
        }
        if (c == 1 && row < NROWS) best64g[row] = 0xFFFFFFFFFFFFFFFFULL;
    }
}

// Main: round-0 shape (512 thr, 8 waves, BM=128, SPLITS=2, 256 blocks, 1/CU)
// but with SWAPPED MFMA operands: mfma(codes, rows) instead of mfma(rows, codes).
// A/B fragments of 16x16x32 have identical lane layouts, so whf/afrag are
// valid in either slot. C layout flips to col=x-row(lane&15),
// row=code((lane>>4)*4+reg): each lane holds 16 codes of ONE row per pass.
// Per-pass row-min is now per-lane VALU fmin + 2 shuffles per rg (16/pass
// total, vs 128 shuffles + 32 LDS atomics + 32 rowmin re-reads before).
// Same approx score formula, same prefix-min + MARGIN + CAP superset
// semantics, bit-identical exact rescore.
__global__ __launch_bounds__(512, 2)
void vq_main(const float* __restrict__ x, const float* __restrict__ w,
             const unsigned short* __restrict__ whf,
             const float* __restrict__ wsq, const float* __restrict__ xsq,
             unsigned long long* __restrict__ best64g) {
    __shared__ unsigned short afrag[8 * 8 * 64 * 8];   // rg,k32,lane -> 16B frag; 64 KB
    __shared__ unsigned rowmin[BM];
    __shared__ int cnt[BM];
    __shared__ int cand[BM][CAP];

    const int tid = threadIdx.x;
    const int lane = tid & 63;
    const int wv = tid >> 6;          // 0..7
    const int lm = lane & 15;
    const int lq = lane >> 4;

    // block -> (split, rowGroup); same-split blocks cluster per XCD (L2 locality)
    const int blk = blockIdx.x;
    const int xcd = blk & 7;
    const int split = xcd & 1;
    const int rowGroup = (xcd >> 1) * 32 + (blk >> 3);   // bijective 0..127 per split
    const int rowBase = rowGroup * BM;
    const int codeBase = split * CPB;

    if (tid < BM) { rowmin[tid] = 0xFFFFFFFFu; cnt[tid] = 0; }

    // ---- stage A tile once (bf16, fragment order); wave wv handles rg=wv ----
    {
        const int rg = wv;
        const float* xr = x + (size_t)(rowBase + rg * 16 + lm) * DIM + lq * 8;
        #pragma unroll
        for (int k32 = 0; k32 < 8; ++k32) {
            float4 u0 = *reinterpret_cast<const float4*>(xr + k32 * 32);
            float4 u1 = *reinterpret_cast<const float4*>(xr + k32 * 32 + 4);
            unsigned short t8[8];
            t8[0] = f2bf(u0.x); t8[1] = f2bf(u0.y); t8[2] = f2bf(u0.z); t8[3] = f2bf(u0.w);
            t8[4] = f2bf(u1.x); t8[5] = f2bf(u1.y); t8[6] = f2bf(u1.z); t8[7] = f2bf(u1.w);
            *reinterpret_cast<uint4*>(afrag + ((rg * 8 + k32) * 64 + lane) * 8) =
                *reinterpret_cast<uint4*>(t8);
        }
    }
    __syncthreads();   // the ONLY barrier before the final reduction

    const int waveCode16 = (codeBase >> 4) + wv * 32;    // base c16 for this wave

    for (int p = 0; p < 8; ++p) {                        // 8 passes x 64 codes
        const int pbase16 = waveCode16 + p * 4;
        f32x4 acc[8][4];
        #pragma unroll
        for (int rg = 0; rg < 8; ++rg)
            #pragma unroll
            for (int cf = 0; cf < 4; ++cf)
                acc[rg][cf] = (f32x4){0.f, 0.f, 0.f, 0.f};

        // wsq for this lane's 16 codes: code = (pbase16+cf)*16 + lq*4 + r
        float wq[4][4];
        #pragma unroll
        for (int cf = 0; cf < 4; ++cf)
            #pragma unroll
            for (int r = 0; r < 4; ++r)
                wq[cf][r] = wsq[(pbase16 + cf) * 16 + lq * 4 + r];

        bf16x8 bb[2][4];
        #pragma unroll
        for (int cf = 0; cf < 4; ++cf)
            bb[0][cf] = *reinterpret_cast<const bf16x8*>(
                whf + (((size_t)(pbase16 + cf)) * 64 + lane) * 8);

        #pragma unroll
        for (int k32 = 0; k32 < 8; ++k32) {
            const int cur = k32 & 1;
            if (k32 < 7) {
                #pragma unroll
                for (int cf = 0; cf < 4; ++cf)
                    bb[cur ^ 1][cf] = *reinterpret_cast<const bf16x8*>(
                        whf + (((size_t)((k32 + 1) * 512 + pbase16 + cf)) * 64 + lane) * 8);
            }
            bf16x8 a[8];
            #pragma unroll
            for (int rg = 0; rg < 8; ++rg)
                a[rg] = *reinterpret_cast<const bf16x8*>(
                    afrag + ((rg * 8 + k32) * 64 + lane) * 8);
            // SWAPPED: A = codes (bb), B = rows (a). C: col=row(lm), row=code.
            #pragma unroll
            for (int cf = 0; cf < 4; ++cf)
                #pragma unroll
                for (int rg = 0; rg < 8; ++rg)
                    acc[rg][cf] = __builtin_amdgcn_mfma_f32_16x16x32_bf16(
                        bb[cur][cf], a[rg], acc[rg][cf], 0, 0, 0);
        }

        // ---- approx score: s = wsq - 2*dot; acc[rg][cf][r] is row rg*16+lm,
        //      code (pbase16+cf)*16 + lq*4 + r ----
        float mloc[8];
        #pragma unroll
        for (int rg = 0; rg < 8; ++rg) {
            float mpl = __builtin_huge_valf();
            #pragma unroll
            for (int cf = 0; cf < 4; ++cf)
                #pragma unroll
                for (int r = 0; r < 4; ++r)
                    mpl = fminf(mpl, fmaf(-2.f, acc[rg][cf][r], wq[cf][r]));
            mloc[rg] = mpl;
            float rm = fminf(mpl, __shfl_xor(mpl, 16, 64));
            rm = fminf(rm, __shfl_xor(rm, 32, 64));
            if (lq == 0)
                atomicMin(&rowmin[rg * 16 + lm], f2ord(rm));
        }
        // collect candidates vs prefix min (stale rowmin => superset, safe)
        #pragma unroll
        for (int rg = 0; rg < 8; ++rg) {
            const int row = rg * 16 + lm;
            float limit = ord2f(rowmin[row]) + MARGIN;
            if (mloc[rg] <= limit) {
                #pragma unroll
                for (int cf = 0; cf < 4; ++cf)
                    #pragma unroll
                    for (int r = 0; r < 4; ++r) {
                        float s = fmaf(-2.f, acc[rg][cf][r], wq[cf][r]);
                        if (s <= limit) {
                            int pos = atomicAdd(&cnt[row], 1);
                            if (pos < CAP)
                                cand[row][pos] = (pbase16 + cf) * 16 + lq * 4 + r;
                        }
                    }
            }
        }
    }
    __syncthreads();

    // ---- exact rescore (bit-identical to round-2 validated formula) ----
    for (int slot = tid; slot < BM * CAP; slot += 512) {
        int row = slot / CAP, pos = slot - (slot / CAP) * CAP;
        int n = cnt[row] < CAP ? cnt[row] : CAP;
        if (pos < n) {
            int c = cand[row][pos];
            const float* xr = x + (size_t)(rowBase + row) * DIM;
            const float* wr = w + (size_t)c * DIM;
            float d = 0.f;
            for (int k = 0; k < DIM; k += 4) {
                float4 a = *reinterpret_cast<const float4*>(xr + k);
                float4 b = *reinterpret_cast<const float4*>(wr + k);
                d = fmaf(a.x, b.x, d);
                d = fmaf(a.y, b.y, d);
                d = fmaf(a.z, b.z, d);
                d = fmaf(a.w, b.w, d);
            }
            float t1 = __fadd_rn(xsq[rowBase + row], wsq[c]);
            float s = __fsub_rn(t1, __fadd_rn(d, d));
            unsigned long long key =
                ((unsigned long long)__float_as_uint(s) << 32) | (unsigned)c;
            atomicMin(best64g + rowBase + row, key);   // s>0: bit order = float order
        }
    }
}

// Final: read per-row best key, write index + gather codeword.
__global__ __launch_bounds__(256)
void out_kernel(const float* __restrict__ w,
                const unsigned long long* __restrict__ best64g,
                float* __restrict__ out_q, float* __restrict__ out_idx) {
    int r = blockIdx.x * 4 + (threadIdx.x >> 6);
    int lane = threadIdx.x & 63;
    unsigned long long key = best64g[r];
    int idx = (int)(key & 0xFFFFFFFFu);
    float4 v = reinterpret_cast<const float4*>(w + (size_t)idx * DIM)[lane];
    reinterpret_cast<float4*>(out_q + (size_t)r * DIM)[lane] = v;
    if (lane == 0) out_idx[r] = (float)idx;
}

extern "C" void kernel_launch(void* const* d_in, const int* in_sizes, int n_in,
                              void* d_out, int out_size, void* d_ws, size_t ws_size,
                              hipStream_t stream) {
    const float* x = (const float*)d_in[0];   // (16384, 256) fp32
    const float* w = (const float*)d_in[1];   // (8192, 256) fp32
    float* out_q = (float*)d_out;
    float* out_idx = (float*)d_out + (size_t)NROWS * DIM;

    unsigned short* whf = (unsigned short*)d_ws;                      // 4 MB
    float* wsq = (float*)((char*)d_ws + (size_t)NCODES * DIM * 2);    // 32 KB
    float* xsq = wsq + NCODES;                                        // 64 KB
    unsigned long long* best64g = (unsigned long long*)(xsq + NROWS); // 128 KB

    prep_kernel<<<WFRAG_BLOCKS + SQ_BLOCKS, 256, 0, stream>>>(x, w, whf, xsq, wsq, best64g);
    vq_main<<<(NROWS / BM) * SPLITS, 512, 0, stream>>>(x, w, whf, wsq, xsq, best64g);
    out_kernel<<<NROWS / 4, 256, 0, stream>>>(w, best64g, out_q, out_idx);
}

// Round 3
// 226.308 us; speedup vs baseline: 1.4670x; 1.0155x over previous
//
#include <hip/hip_runtime.h>
#include <hip/hip_bf16.h>

#define NROWS 16384
#define NCODES 8192
#define DIM 256
#define BM 128                     // rows per block
#define SPLITS 2
#define CPB (NCODES / SPLITS)      // 4096 codes per block
#define CAP 24
#define MARGIND 1.7e-4f            // dot-scale margin (= old 3e-4 s-scale /2 + slack)

#define WFRAG_BLOCKS 1024          // 8192*256/8 / 256
#define SQ_BLOCKS 1536             // (16384+8192) rows / 16 per block

typedef __attribute__((ext_vector_type(8))) short bf16x8;
typedef __attribute__((ext_vector_type(4))) float f32x4;

__device__ inline unsigned short f2bf(float f) {
    union { __hip_bfloat16 h; unsigned short u; } cv;
    cv.h = __float2bfloat16(f);
    return cv.u;
}
__device__ inline unsigned f2ord(float f) {
    unsigned u = __float_as_uint(f);
    return u ^ ((u >> 31) ? 0xFFFFFFFFu : 0x80000000u);
}
__device__ inline float ord2f(unsigned u) {
    unsigned v = (u & 0x80000000u) ? (u ^ 0x80000000u) : ~u;
    return __uint_as_float(v);
}

// Fused prep:
//  blocks [0, WFRAG_BLOCKS): pre-swizzle W into MFMA fragment order (bf16),
//    NOW c16-major so each wave's per-pass stream is contiguous:
//    flat unit tid = (c16*8 + k32)*64 + L holds 8 bf16 =
//      W[c16*16 + (L&15)][k32*32 + (L>>4)*8 + j]
//  blocks [WFRAG_BLOCKS, +SQ_BLOCKS): xsq/wsq via the EXACT pairwise256 tree,
//    16 lanes/row, shfl-xor combine (bit-exact; fp add operand-commutative).
//    Also initializes best64g (replaces hipMemsetAsync).
__global__ __launch_bounds__(256)
void prep_kernel(const float* __restrict__ x, const float* __restrict__ w,
                 unsigned short* __restrict__ whf,
                 float* __restrict__ xsq, float* __restrict__ wsq,
                 unsigned long long* __restrict__ best64g) {
    if (blockIdx.x < WFRAG_BLOCKS) {
        int tid = blockIdx.x * 256 + threadIdx.x;   // 0 .. 262143
        int L = tid & 63;
        int rest = tid >> 6;
        int k32 = rest & 7;
        int c16 = rest >> 3;
        int code = c16 * 16 + (L & 15);
        int k = k32 * 32 + (L >> 4) * 8;
        const float4* p = reinterpret_cast<const float4*>(w + (size_t)code * DIM + k);
        float4 u0 = p[0], u1 = p[1];
        unsigned short tmp[8];
        tmp[0] = f2bf(u0.x); tmp[1] = f2bf(u0.y); tmp[2] = f2bf(u0.z); tmp[3] = f2bf(u0.w);
        tmp[4] = f2bf(u1.x); tmp[5] = f2bf(u1.y); tmp[6] = f2bf(u1.z); tmp[7] = f2bf(u1.w);
        *reinterpret_cast<uint4*>(whf + (size_t)tid * 8) = *reinterpret_cast<uint4*>(tmp);
    } else {
        int blk = blockIdx.x - WFRAG_BLOCKS;
        int row = blk * 16 + (threadIdx.x >> 4);     // 0 .. 24575
        int c = threadIdx.x & 15;
        int j = c & 7, h = c >> 3;
        const float* src = (row < NROWS) ? (x + (size_t)row * DIM)
                                         : (w + (size_t)(row - NROWS) * DIM);
        const float* base = src + h * 128 + j;
        float r = 0.0f;
        #pragma unroll
        for (int g = 0; g < 16; ++g) {
            float v = base[g * 8];
            r = __fadd_rn(r, __fmul_rn(v, v));
        }
        float t;
        t = __shfl_xor(r, 1, 64); r = __fadd_rn(r, t);   // (r_j + r_{j^1})
        t = __shfl_xor(r, 2, 64); r = __fadd_rn(r, t);   // (r0+r1)+(r2+r3)
        t = __shfl_xor(r, 4, 64); r = __fadd_rn(r, t);   // half sum
        t = __shfl_xor(r, 8, 64); r = __fadd_rn(r, t);   // res0 + res1
        if (c == 0) {
            if (row < NROWS) xsq[row] = r;
            else wsq[row - NROWS] = r;
        }
        if (c == 1 && row < NROWS) best64g[row] = 0xFFFFFFFFFFFFFFFFULL;
    }
}

// Main: swapped-operand MFMA (A=codes, B=rows; C: col=x-row(lane&15),
// row=code((lane>>4)*4+reg)). Approx phase now tracks MAX DOT per row
// (wsq dropped: max wsq ~1.3e-9 vs score scale ~1e-3; MARGIND covers it).
// Candidate set = prefix-max superset, exact f32 rescore unchanged.
// whf re-laid out c16-major: per-pass stream is contiguous 32 KB; all bb
// loads = one base + constant offsets, all afrag ds_reads = one addr reg +
// 16-bit immediate offsets. Register budget ~100 VGPR + 128 AGPR < 256.
__global__ __launch_bounds__(512, 2)
void vq_main(const float* __restrict__ x, const float* __restrict__ w,
             const unsigned short* __restrict__ whf,
             const float* __restrict__ wsq, const float* __restrict__ xsq,
             unsigned long long* __restrict__ best64g) {
    __shared__ unsigned short afrag[8 * 8 * 64 * 8];   // rg,k32,lane -> 16B frag; 64 KB
    __shared__ unsigned rowmax[BM];                    // ordered-uint max of dot
    __shared__ int cnt[BM];
    __shared__ int cand[BM][CAP];

    const int tid = threadIdx.x;
    const int lane = tid & 63;
    const int wv = tid >> 6;          // 0..7
    const int lm = lane & 15;
    const int lq = lane >> 4;

    // block -> (split, rowGroup); same-split blocks cluster per XCD (L2 locality)
    const int blk = blockIdx.x;
    const int xcd = blk & 7;
    const int split = xcd & 1;
    const int rowGroup = (xcd >> 1) * 32 + (blk >> 3);   // bijective 0..127 per split
    const int rowBase = rowGroup * BM;
    const int codeBase = split * CPB;

    if (tid < BM) { rowmax[tid] = 0u; cnt[tid] = 0; }

    // ---- stage A tile once (bf16, fragment order); wave wv handles rg=wv ----
    {
        const int rg = wv;
        const float* xr = x + (size_t)(rowBase + rg * 16 + lm) * DIM + lq * 8;
        #pragma unroll
        for (int k32 = 0; k32 < 8; ++k32) {
            float4 u0 = *reinterpret_cast<const float4*>(xr + k32 * 32);
            float4 u1 = *reinterpret_cast<const float4*>(xr + k32 * 32 + 4);
            unsigned short t8[8];
            t8[0] = f2bf(u0.x); t8[1] = f2bf(u0.y); t8[2] = f2bf(u0.z); t8[3] = f2bf(u0.w);
            t8[4] = f2bf(u1.x); t8[5] = f2bf(u1.y); t8[6] = f2bf(u1.z); t8[7] = f2bf(u1.w);
            *reinterpret_cast<uint4*>(afrag + ((rg * 8 + k32) * 64 + lane) * 8) =
                *reinterpret_cast<uint4*>(t8);
        }
    }
    __syncthreads();   // the ONLY barrier before the final reduction

    const unsigned short* afb = afrag + lane * 8;        // all ds_reads: afb + imm
    const int waveCode16 = (codeBase >> 4) + wv * 32;    // base c16 for this wave

    for (int p = 0; p < 8; ++p) {                        // 8 passes x 64 codes
        const int pbase16 = waveCode16 + p * 4;
        // contiguous per-pass stream: element (c16,k32,lane,j) at
        // c16*4096 + k32*512 + lane*8 + j
        const unsigned short* wpass = whf + (size_t)pbase16 * 4096 + lane * 8;

        f32x4 acc[8][4];
        #pragma unroll
        for (int rg = 0; rg < 8; ++rg)
            #pragma unroll
            for (int cf = 0; cf < 4; ++cf)
                acc[rg][cf] = (f32x4){0.f, 0.f, 0.f, 0.f};

        bf16x8 bb[2][4];
        #pragma unroll
        for (int cf = 0; cf < 4; ++cf)
            bb[0][cf] = *reinterpret_cast<const bf16x8*>(wpass + cf * 4096);

        #pragma unroll
        for (int k32 = 0; k32 < 8; ++k32) {
            const int cur = k32 & 1;
            if (k32 < 7) {
                #pragma unroll
                for (int cf = 0; cf < 4; ++cf)
                    bb[cur ^ 1][cf] = *reinterpret_cast<const bf16x8*>(
                        wpass + cf * 4096 + (k32 + 1) * 512);
            }
            bf16x8 a[8];
            #pragma unroll
            for (int rg = 0; rg < 8; ++rg)
                a[rg] = *reinterpret_cast<const bf16x8*>(afb + (rg * 8 + k32) * 512);
            // A = codes (bb), B = rows (a). C: col=row(lm), row=code.
            #pragma unroll
            for (int cf = 0; cf < 4; ++cf)
                #pragma unroll
                for (int rg = 0; rg < 8; ++rg)
                    acc[rg][cf] = __builtin_amdgcn_mfma_f32_16x16x32_bf16(
                        bb[cur][cf], a[rg], acc[rg][cf], 0, 0, 0);
        }

        // ---- epilogue: track max dot per row; candidates = prefix-max superset
        #pragma unroll
        for (int rg = 0; rg < 8; ++rg) {
            float m = -__builtin_huge_valf();
            #pragma unroll
            for (int cf = 0; cf < 4; ++cf)
                #pragma unroll
                for (int r = 0; r < 4; ++r)
                    m = fmaxf(m, acc[rg][cf][r]);
            float rm = fmaxf(m, __shfl_xor(m, 16, 64));
            rm = fmaxf(rm, __shfl_xor(rm, 32, 64));
            const int row = rg * 16 + lm;
            if (lq == 0) atomicMax(&rowmax[row], f2ord(rm));
            // own wave's atomic lands before this read (in-order DS per wave);
            // stale (smaller) cross-wave max => lower limit => superset, safe
            float limit = ord2f(rowmax[row]) - MARGIND;
            if (m >= limit) {
                #pragma unroll
                for (int cf = 0; cf < 4; ++cf)
                    #pragma unroll
                    for (int r = 0; r < 4; ++r) {
                        if (acc[rg][cf][r] >= limit) {
                            int pos = atomicAdd(&cnt[row], 1);
                            if (pos < CAP)
                                cand[row][pos] = (pbase16 + cf) * 16 + lq * 4 + r;
                        }
                    }
            }
        }
    }
    __syncthreads();

    // ---- exact rescore (bit-identical validated formula, f32, incl. wsq) ----
    for (int slot = tid; slot < BM * CAP; slot += 512) {
        int row = slot / CAP, pos = slot - (slot / CAP) * CAP;
        int n = cnt[row] < CAP ? cnt[row] : CAP;
        if (pos < n) {
            int c = cand[row][pos];
            const float* xr = x + (size_t)(rowBase + row) * DIM;
            const float* wr = w + (size_t)c * DIM;
            float d = 0.f;
            for (int k = 0; k < DIM; k += 4) {
                float4 a = *reinterpret_cast<const float4*>(xr + k);
                float4 b = *reinterpret_cast<const float4*>(wr + k);
                d = fmaf(a.x, b.x, d);
                d = fmaf(a.y, b.y, d);
                d = fmaf(a.z, b.z, d);
                d = fmaf(a.w, b.w, d);
            }
            float t1 = __fadd_rn(xsq[rowBase + row], wsq[c]);
            float s = __fsub_rn(t1, __fadd_rn(d, d));
            unsigned long long key =
                ((unsigned long long)__float_as_uint(s) << 32) | (unsigned)c;
            atomicMin(best64g + rowBase + row, key);   // s>0: bit order = float order
        }
    }
}

// Final: read per-row best key, write index + gather codeword.
__global__ __launch_bounds__(256)
void out_kernel(const float* __restrict__ w,
                const unsigned long long* __restrict__ best64g,
                float* __restrict__ out_q, float* __restrict__ out_idx) {
    int r = blockIdx.x * 4 + (threadIdx.x >> 6);
    int lane = threadIdx.x & 63;
    unsigned long long key = best64g[r];
    int idx = (int)(key & 0xFFFFFFFFu);
    float4 v = reinterpret_cast<const float4*>(w + (size_t)idx * DIM)[lane];
    reinterpret_cast<float4*>(out_q + (size_t)r * DIM)[lane] = v;
    if (lane == 0) out_idx[r] = (float)idx;
}

extern "C" void kernel_launch(void* const* d_in, const int* in_sizes, int n_in,
                              void* d_out, int out_size, void* d_ws, size_t ws_size,
                              hipStream_t stream) {
    const float* x = (const float*)d_in[0];   // (16384, 256) fp32
    const float* w = (const float*)d_in[1];   // (8192, 256) fp32
    float* out_q = (float*)d_out;
    float* out_idx = (float*)d_out + (size_t)NROWS * DIM;

    unsigned short* whf = (unsigned short*)d_ws;                      // 4 MB
    float* wsq = (float*)((char*)d_ws + (size_t)NCODES * DIM * 2);    // 32 KB
    float* xsq = wsq + NCODES;                                        // 64 KB
    unsigned long long* best64g = (unsigned long long*)(xsq + NROWS); // 128 KB

    prep_kernel<<<WFRAG_BLOCKS + SQ_BLOCKS, 256, 0, stream>>>(x, w, whf, xsq, wsq, best64g);
    vq_main<<<(NROWS / BM) * SPLITS, 512, 0, stream>>>(x, w, whf, wsq, xsq, best64g);
    out_kernel<<<NROWS / 4, 256, 0, stream>>>(w, best64g, out_q, out_idx);
}